// Round 1
// baseline (300.470 us; speedup 1.0000x reference)
//
#include <hip/hip_runtime.h>

#define SN 6400      // H*W
#define CN 256       // channels (= GEMM K)
#define NBATCH 2
#define NTILES 50    // SN / 128
#define NCHUNK 5     // tile chunks per pass
#define TPC 10       // tiles per chunk

typedef _Float16 f16;
typedef f16 f16x8 __attribute__((ext_vector_type(8)));
typedef float f32x4 __attribute__((ext_vector_type(4)));

__device__ __forceinline__ void gld16(const f16* g, f16* l) {
    __builtin_amdgcn_global_load_lds(
        (__attribute__((address_space(1))) void*)(g),
        (__attribute__((address_space(3))) void*)(l), 16, 0, 0);
}

// ---------------- prep kernels ----------------

// per-channel mean of T over (N,H,W): one block per channel
__global__ __launch_bounds__(256) void k_meanT(const float* __restrict__ T,
                                               float* __restrict__ meanT) {
    int c = blockIdx.x, t = threadIdx.x;
    const float* p0 = T + (size_t)c * SN;            // n=0
    const float* p1 = T + (size_t)(CN + c) * SN;     // n=1
    float s = 0.f;
    for (int i = t; i < SN; i += 256) s += p0[i] + p1[i];
    #pragma unroll
    for (int d = 1; d < 64; d <<= 1) s += __shfl_xor(s, d, 64);
    __shared__ float sb[4];
    if ((t & 63) == 0) sb[t >> 6] = s;
    __syncthreads();
    if (t == 0) meanT[c] = (sb[0] + sb[1] + sb[2] + sb[3]) * (1.0f / 12800.0f);
}

// inverse channel-norms of centered I and T at every (n,s)
__global__ __launch_bounds__(256) void k_norms(const float* __restrict__ I,
                                               const float* __restrict__ T,
                                               const float* __restrict__ meanT,
                                               float* __restrict__ invNI,
                                               float* __restrict__ invNT) {
    int idx = blockIdx.x * 256 + threadIdx.x;        // 0..12799, n uniform per block
    int n = idx / SN, s = idx - n * SN;
    __shared__ float mt[CN];
    for (int c = threadIdx.x; c < CN; c += 256) mt[c] = meanT[c];
    __syncthreads();
    const float* Ib = I + (size_t)n * CN * SN + s;
    const float* Tb = T + (size_t)n * CN * SN + s;
    float si = 0.f, st = 0.f;
    for (int c = 0; c < CN; ++c) {
        float a = Ib[(size_t)c * SN] - mt[c]; si += a * a;
        float b = Tb[(size_t)c * SN] - mt[c]; st += b * b;
    }
    invNI[idx] = rsqrtf(si);
    invNT[idx] = rsqrtf(st);
}

// transpose [n,c,s] -> [n,s,c], center, normalize, cast to fp16
__global__ __launch_bounds__(256) void k_xpose(const float* __restrict__ X,
                                               const float* __restrict__ meanT,
                                               const float* __restrict__ invN,
                                               f16* __restrict__ out) {
    int n = blockIdx.z, c0 = blockIdx.y * 32, s0 = blockIdx.x * 64;
    __shared__ float tile[32][65];
    int tx = threadIdx.x & 63, ty = threadIdx.x >> 6;       // ty 0..3
    const float* Xb = X + ((size_t)n * CN + c0) * SN + s0;
    #pragma unroll
    for (int cy = ty; cy < 32; cy += 4)
        tile[cy][tx] = Xb[(size_t)cy * SN + tx] - meanT[c0 + cy];
    __syncthreads();
    int cc = threadIdx.x & 31, sy = threadIdx.x >> 5;       // sy 0..7
    f16* ob = out + ((size_t)n * SN + s0) * CN + c0;
    const float* invb = invN + (size_t)n * SN + s0;
    #pragma unroll
    for (int sr = sy; sr < 64; sr += 8)
        ob[(size_t)sr * CN + cc] = (f16)(tile[cc][sr] * invb[sr]);
}

// ---------------- fused GEMM passes ----------------
// PASS 0: per-row max of cos            -> rowmaxP[n][chunk][i]
// PASS 1: per-row sum of w=exp(10-g*raw)-> rowsumP[n][chunk][i]
// PASS 2: per-col max of log(cs)        -> colmaxP[n][chunk][j]
template <int PASS>
__global__ __launch_bounds__(256, 2) void k_gemm(const f16* __restrict__ A,
                                                 const f16* __restrict__ B,
                                                 const float* __restrict__ grow,
                                                 const float* __restrict__ alpha,
                                                 float* __restrict__ outP) {
    const int n = blockIdx.z;
    const int chunk = blockIdx.y;
    const int fixedTile = blockIdx.x;   // i-tile (PASS 0/1) or j-tile (PASS 2)
    const int tid = threadIdx.x;
    const int lane = tid & 63;
    const int wv = tid >> 6;
    const int wr = wv >> 1, wc = wv & 1;
    const int quad = lane >> 4, lrow = lane & 15;

    __shared__ f16 Abuf[128 * 32];
    __shared__ f16 Bbuf[128 * 32];
    __shared__ float redbuf[2][128];

    const f16* Anb = A + (size_t)n * SN * CN;
    const f16* Bnb = B + (size_t)n * SN * CN;

    float runRow[4][4];
    float runCol[4];
    #pragma unroll
    for (int mt = 0; mt < 4; ++mt)
        #pragma unroll
        for (int v = 0; v < 4; ++v) runRow[mt][v] = (PASS == 1) ? 0.f : -3.0e38f;
    #pragma unroll
    for (int nt = 0; nt < 4; ++nt) runCol[nt] = -3.0e38f;

    const float L2E = 1.44269504089f;
    float a0c[4][4], a1c[4][4];
    if constexpr (PASS == 1) {
        #pragma unroll
        for (int mt = 0; mt < 4; ++mt)
            #pragma unroll
            for (int v = 0; v < 4; ++v) {
                int r = fixedTile * 128 + wr * 64 + mt * 16 + quad * 4 + v;
                float gg = grow[(size_t)n * SN + r];
                a1c[mt][v] = 0.5f * gg * L2E;
                a0c[mt][v] = (10.f - 0.5f * gg) * L2E;
            }
    }

    for (int t = 0; t < TPC; ++t) {
        int other = chunk * TPC + t;
        int it = (PASS == 2) ? other : fixedTile;
        int jt = (PASS == 2) ? fixedTile : other;
        const f16* Abase = Anb + (size_t)it * 128 * CN;
        const f16* Bbase = Bnb + (size_t)jt * 128 * CN;

        f32x4 acc[4][4];
        #pragma unroll
        for (int mt = 0; mt < 4; ++mt)
            #pragma unroll
            for (int nt = 0; nt < 4; ++nt) acc[mt][nt] = (f32x4){0.f, 0.f, 0.f, 0.f};

        for (int kk = 0; kk < 8; ++kk) {
            const int k0 = kk * 32;
            #pragma unroll
            for (int r = 0; r < 2; ++r) {
                int q = r * 256 + tid;
                int row = q >> 2, kq = q & 3;
                const f16* ga = Abase + (size_t)row * CN + k0 + kq * 8;
                const f16* gb = Bbase + (size_t)row * CN + k0 + kq * 8;
                int lo = (r * 256 + (tid & 192)) * 8;   // wave-uniform LDS base (elems)
                gld16(ga, &Abuf[lo]);
                gld16(gb, &Bbuf[lo]);
            }
            __syncthreads();
            f16x8 af[4], bfv[4];
            #pragma unroll
            for (int mt = 0; mt < 4; ++mt)
                af[mt] = *(const f16x8*)&Abuf[(wr * 64 + mt * 16 + lrow) * 32 + quad * 8];
            #pragma unroll
            for (int nt = 0; nt < 4; ++nt)
                bfv[nt] = *(const f16x8*)&Bbuf[(wc * 64 + nt * 16 + lrow) * 32 + quad * 8];
            #pragma unroll
            for (int mt = 0; mt < 4; ++mt)
                #pragma unroll
                for (int nt = 0; nt < 4; ++nt)
                    acc[mt][nt] = __builtin_amdgcn_mfma_f32_16x16x32_f16(
                        af[mt], bfv[nt], acc[mt][nt], 0, 0, 0);
            __syncthreads();
        }

        // per-tile epilogue (registers only)
        if constexpr (PASS == 0) {
            #pragma unroll
            for (int mt = 0; mt < 4; ++mt)
                #pragma unroll
                for (int v = 0; v < 4; ++v) {
                    float m = fmaxf(fmaxf(acc[mt][0][v], acc[mt][1][v]),
                                    fmaxf(acc[mt][2][v], acc[mt][3][v]));
                    runRow[mt][v] = fmaxf(runRow[mt][v], m);
                }
        } else if constexpr (PASS == 1) {
            #pragma unroll
            for (int mt = 0; mt < 4; ++mt)
                #pragma unroll
                for (int v = 0; v < 4; ++v) {
                    float s = runRow[mt][v];
                    #pragma unroll
                    for (int nt = 0; nt < 4; ++nt) {
                        float arg = fminf(14.4269504089f,
                                          fmaf(acc[mt][nt][v], a1c[mt][v], a0c[mt][v]));
                        s += exp2f(arg);
                    }
                    runRow[mt][v] = s;
                }
        } else {
            #pragma unroll
            for (int mt = 0; mt < 4; ++mt)
                #pragma unroll
                for (int v = 0; v < 4; ++v) {
                    int r = it * 128 + wr * 64 + mt * 16 + quad * 4 + v;
                    float al = alpha[(size_t)n * SN + r];
                    float gg = grow[(size_t)n * SN + r];
                    #pragma unroll
                    for (int nt = 0; nt < 4; ++nt) {
                        float raw = fmaxf(0.f, fmaf(acc[mt][nt][v], -0.5f, 0.5f));
                        float lc = fmaf(-gg, raw, al);
                        runCol[nt] = fmaxf(runCol[nt], lc);
                    }
                }
        }
    }

    // cross-lane / cross-wave reduction and partial write
    if constexpr (PASS == 0 || PASS == 1) {
        #pragma unroll
        for (int mt = 0; mt < 4; ++mt)
            #pragma unroll
            for (int v = 0; v < 4; ++v) {
                float val = runRow[mt][v];
                #pragma unroll
                for (int d = 1; d < 16; d <<= 1) {
                    float o = __shfl_xor(val, d, 64);
                    val = (PASS == 0) ? fmaxf(val, o) : (val + o);
                }
                if (lrow == 0) redbuf[wc][wr * 64 + mt * 16 + quad * 4 + v] = val;
            }
        __syncthreads();
        if (tid < 128) {
            float a = redbuf[0][tid], b = redbuf[1][tid];
            outP[(size_t)(n * NCHUNK + chunk) * SN + fixedTile * 128 + tid] =
                (PASS == 0) ? fmaxf(a, b) : (a + b);
        }
    } else {
        #pragma unroll
        for (int nt = 0; nt < 4; ++nt) {
            float val = runCol[nt];
            val = fmaxf(val, __shfl_xor(val, 16, 64));
            val = fmaxf(val, __shfl_xor(val, 32, 64));
            if (quad == 0) redbuf[wr][wc * 64 + nt * 16 + lrow] = val;
        }
        __syncthreads();
        if (tid < 128) {
            float cm = fmaxf(redbuf[0][tid], redbuf[1][tid]);
            outP[(size_t)(n * NCHUNK + chunk) * SN + fixedTile * 128 + tid] = cm;
        }
    }
}

// ---------------- small reduce kernels ----------------

__global__ __launch_bounds__(256) void r_g(const float* __restrict__ rowmaxP,
                                           float* __restrict__ grow) {
    int idx = blockIdx.x * 256 + threadIdx.x;
    int n = idx / SN, i = idx - n * SN;
    float m = -3.0e38f;
    for (int ch = 0; ch < NCHUNK; ++ch)
        m = fmaxf(m, rowmaxP[(size_t)(n * NCHUNK + ch) * SN + i]);
    float mr = fmaxf(0.f, (1.f - m) * 0.5f);        // min_j raw
    grow[idx] = 10.f / (mr + 1e-5f);
}

__global__ __launch_bounds__(256) void r_alpha(const float* __restrict__ rowsumP,
                                               float* __restrict__ alpha) {
    int idx = blockIdx.x * 256 + threadIdx.x;
    int n = idx / SN, i = idx - n * SN;
    float s = 0.f;
    for (int ch = 0; ch < NCHUNK; ++ch)
        s += rowsumP[(size_t)(n * NCHUNK + ch) * SN + i];
    alpha[idx] = 10.f - logf(s);
}

__global__ __launch_bounds__(256) void r_colfin(const float* __restrict__ colmaxP,
                                                float* __restrict__ bsum) {
    int idx = blockIdx.x * 256 + threadIdx.x;
    int n = idx / SN, j = idx - n * SN;
    float m = -3.0e38f;
    for (int ch = 0; ch < NCHUNK; ++ch)
        m = fmaxf(m, colmaxP[(size_t)(n * NCHUNK + ch) * SN + j]);
    float v = expf(m);                               // max_i cs[i,j]
    #pragma unroll
    for (int d = 1; d < 64; d <<= 1) v += __shfl_xor(v, d, 64);
    __shared__ float sb[4];
    if ((threadIdx.x & 63) == 0) sb[threadIdx.x >> 6] = v;
    __syncthreads();
    if (threadIdx.x == 0) bsum[blockIdx.x] = sb[0] + sb[1] + sb[2] + sb[3];
}

__global__ __launch_bounds__(64) void r_loss(const float* __restrict__ bsum,
                                             float* __restrict__ out) {
    int t = threadIdx.x;
    float v = (t < 50) ? bsum[t] : 0.f;
    float v0 = (t < 25) ? v : 0.f;                   // n=0 blocks
    float v1 = (t >= 25 && t < 50) ? v : 0.f;        // n=1 blocks
    #pragma unroll
    for (int d = 1; d < 64; d <<= 1) {
        v0 += __shfl_xor(v0, d, 64);
        v1 += __shfl_xor(v1, d, 64);
    }
    if (t == 0) {
        float cs0 = v0 * (1.0f / SN), cs1 = v1 * (1.0f / SN);
        out[0] = -0.5f * (logf(cs0) + logf(cs1));
    }
}

// ---------------- launch ----------------

extern "C" void kernel_launch(void* const* d_in, const int* in_sizes, int n_in,
                              void* d_out, int out_size, void* d_ws, size_t ws_size,
                              hipStream_t stream) {
    const float* I = (const float*)d_in[0];
    const float* T = (const float*)d_in[1];
    float* out = (float*)d_out;

    float* wsf = (float*)d_ws;
    float* meanT = wsf;                       // 256
    float* invNI = meanT + 256;               // 12800
    float* invNT = invNI + 12800;             // 12800
    float* grow  = invNT + 12800;             // 12800
    float* alpha = grow + 12800;              // 12800
    float* rowmaxP = alpha + 12800;           // 64000
    float* rowsumP = rowmaxP + 64000;         // 64000
    float* colmaxP = rowsumP + 64000;         // 64000
    float* bsum = colmaxP + 64000;            // 64
    f16* Ah = (f16*)(bsum + 64);              // 2*6400*256 fp16
    f16* Bh = Ah + (size_t)NBATCH * SN * CN;  // total ws use ~14.1 MB

    k_meanT<<<256, 256, 0, stream>>>(T, meanT);
    k_norms<<<50, 256, 0, stream>>>(I, T, meanT, invNI, invNT);
    k_xpose<<<dim3(100, 8, 2), 256, 0, stream>>>(I, meanT, invNI, Ah);
    k_xpose<<<dim3(100, 8, 2), 256, 0, stream>>>(T, meanT, invNT, Bh);

    dim3 gg(NTILES, NCHUNK, NBATCH);
    k_gemm<0><<<gg, 256, 0, stream>>>(Ah, Bh, nullptr, nullptr, rowmaxP);
    r_g<<<50, 256, 0, stream>>>(rowmaxP, grow);
    k_gemm<1><<<gg, 256, 0, stream>>>(Ah, Bh, grow, nullptr, rowsumP);
    r_alpha<<<50, 256, 0, stream>>>(rowsumP, alpha);
    k_gemm<2><<<gg, 256, 0, stream>>>(Ah, Bh, grow, alpha, colmaxP);
    r_colfin<<<50, 256, 0, stream>>>(colmaxP, bsum);
    r_loss<<<1, 64, 0, stream>>>(bsum, out);
}

// Round 2
// 289.566 us; speedup vs baseline: 1.0377x; 1.0377x over previous
//
#include <hip/hip_runtime.h>

#define SN 6400      // H*W
#define CN 256       // channels (= GEMM K)
#define NBATCH 2
#define NTILES 50    // SN / 128
#define NCHUNK 5     // tile chunks per pass
#define TPC 10       // tiles per chunk

typedef _Float16 f16;
typedef f16 f16x8 __attribute__((ext_vector_type(8)));
typedef f16 f16x4 __attribute__((ext_vector_type(4)));
typedef float f32x4 __attribute__((ext_vector_type(4)));

__device__ __forceinline__ void gld16(const f16* g, f16* l) {
    __builtin_amdgcn_global_load_lds(
        (__attribute__((address_space(1))) void*)(g),
        (__attribute__((address_space(3))) void*)(l), 16, 0, 0);
}

// stage one 128-row x 128-K half-tile (32 KB) into LDS buffer.
// LDS layout: row-major, 128 halfs/row, 16B chunks XOR-swizzled by (row&7)
// (swizzle applied by permuting the global source chunk; DMA lane->LDS map is fixed).
__device__ __forceinline__ void stage_half(const f16* __restrict__ gbase, int h,
                                           f16* lbase, int tid) {
    #pragma unroll
    for (int it = 0; it < 8; ++it) {
        int q = it * 256 + tid;
        int row = q >> 4, c = q & 15;
        int cg = c ^ (row & 7);
        gld16(gbase + (size_t)row * CN + h * 128 + cg * 8,
              lbase + (size_t)(q & ~63) * 8);
    }
}

// ---------------- prep kernels ----------------

__global__ __launch_bounds__(256) void k_meanT(const float* __restrict__ T,
                                               float* __restrict__ meanT) {
    int c = blockIdx.x, t = threadIdx.x;
    const float* p0 = T + (size_t)c * SN;
    const float* p1 = T + (size_t)(CN + c) * SN;
    float s = 0.f;
    for (int i = t; i < SN; i += 256) s += p0[i] + p1[i];
    #pragma unroll
    for (int d = 1; d < 64; d <<= 1) s += __shfl_xor(s, d, 64);
    __shared__ float sb[4];
    if ((t & 63) == 0) sb[t >> 6] = s;
    __syncthreads();
    if (t == 0) meanT[c] = (sb[0] + sb[1] + sb[2] + sb[3]) * (1.0f / 12800.0f);
}

// transpose [n,c,s] -> [n,s,c], center, cast to fp16 (NOT normalized yet)
__global__ __launch_bounds__(256) void k_xpose(const float* __restrict__ X,
                                               const float* __restrict__ meanT,
                                               f16* __restrict__ out) {
    int n = blockIdx.z, c0 = blockIdx.y * 32, s0 = blockIdx.x * 64;
    __shared__ float tile[32][65];
    int tx = threadIdx.x & 63, ty = threadIdx.x >> 6;
    const float* Xb = X + ((size_t)n * CN + c0) * SN + s0;
    #pragma unroll
    for (int cy = ty; cy < 32; cy += 4)
        tile[cy][tx] = Xb[(size_t)cy * SN + tx] - meanT[c0 + cy];
    __syncthreads();
    int cc = threadIdx.x & 31, sy = threadIdx.x >> 5;
    f16* ob = out + ((size_t)n * SN + s0) * CN + c0;
    #pragma unroll
    for (int sr = sy; sr < 64; sr += 8)
        ob[(size_t)sr * CN + cc] = (f16)tile[cc][sr];
}

// rsqrt of sum-of-squares per row of the centered fp16 arrays (one wave per row)
__global__ __launch_bounds__(256) void k_rs(const f16* __restrict__ Ah,
                                            const f16* __restrict__ Bh,
                                            float* __restrict__ sI,
                                            float* __restrict__ sT) {
    int w = threadIdx.x >> 6, lane = threadIdx.x & 63;
    int idx = blockIdx.x * 4 + w;
    f16x4 a = *(const f16x4*)(Ah + (size_t)idx * CN + lane * 4);
    f16x4 b = *(const f16x4*)(Bh + (size_t)idx * CN + lane * 4);
    float sa = 0.f, sb = 0.f;
    #pragma unroll
    for (int j = 0; j < 4; ++j) {
        float x = (float)a[j]; sa += x * x;
        float y = (float)b[j]; sb += y * y;
    }
    #pragma unroll
    for (int d = 1; d < 64; d <<= 1) {
        sa += __shfl_xor(sa, d, 64);
        sb += __shfl_xor(sb, d, 64);
    }
    if (lane == 0) { sI[idx] = rsqrtf(sa); sT[idx] = rsqrtf(sb); }
}

// in-place normalize fp16 rows by fp32 scale
__global__ __launch_bounds__(256) void k_scale(f16* __restrict__ X,
                                               const float* __restrict__ s) {
    int id8 = blockIdx.x * 256 + threadIdx.x;
    int row = id8 >> 5;
    float sc = s[row];
    f16x8 v = *(f16x8*)(X + (size_t)id8 * 8);
    #pragma unroll
    for (int j = 0; j < 8; ++j) v[j] = (f16)((float)v[j] * sc);
    *(f16x8*)(X + (size_t)id8 * 8) = v;
}

// ---------------- fused GEMM passes ----------------
// Fixed tile = MFMA A operand (rows of C); loop tiles = B operand (cols).
// PASS 0: per-row max of cos                      (fixed = I rows i)
// PASS 1: per-row sum of exp((10 - g_i*raw)/ln2)  (fixed = I rows i)
// PASS 2: per-row max over cols of (alpha_c - g_c*raw)  (fixed = T rows j, cols = i)
template <int PASS>
__global__ __launch_bounds__(256, 1) void k_gemm(const f16* __restrict__ A,
                                                 const f16* __restrict__ B,
                                                 const float* __restrict__ grow,
                                                 const float* __restrict__ alpha,
                                                 float* __restrict__ outP) {
    const int n = blockIdx.z, chunk = blockIdx.y, ft = blockIdx.x;
    const int tid = threadIdx.x, lane = tid & 63, wv = tid >> 6;
    const int wr = wv >> 1, wc = wv & 1, quad = lane >> 4, lrow = lane & 15;

    __shared__ f16 buf[2][16384];   // 2 x 32 KB double buffer (exactly 64 KB)

    const f16* Fb = A + ((size_t)n * SN + (size_t)ft * 128) * CN;
    const f16* Lnb = B + (size_t)n * SN * CN;

    // ---- prologue: fixed-tile fragments -> registers (128 VGPRs) ----
    f16x8 af[4][8];
    stage_half(Fb, 0, buf[0], tid);
    __syncthreads();                              // Fh0 in buf0
    stage_half(Fb, 1, buf[1], tid);               // DMA Fh1 while reading buf0
    #pragma unroll
    for (int mt = 0; mt < 4; ++mt) {
        int row = wr * 64 + mt * 16 + lrow;
        #pragma unroll
        for (int kk = 0; kk < 4; ++kk)
            af[mt][kk] = *(const f16x8*)&buf[0][row * 128 + ((kk * 4 + quad) ^ (row & 7)) * 8];
    }
    __syncthreads();                              // Fh1 ready; buf0 reads done
    stage_half(Lnb + (size_t)(chunk * TPC) * 128 * CN, 0, buf[0], tid);
    #pragma unroll
    for (int mt = 0; mt < 4; ++mt) {
        int row = wr * 64 + mt * 16 + lrow;
        #pragma unroll
        for (int kk = 0; kk < 4; ++kk)
            af[mt][4 + kk] = *(const f16x8*)&buf[1][row * 128 + ((kk * 4 + quad) ^ (row & 7)) * 8];
    }
    __syncthreads();                              // L0h0 ready; buf1 reads done

    // PASS1 per-row exp coefficients (rows fixed for whole block)
    const float L2E = 1.44269504089f;
    float a0c[4][4], a1c[4][4];
    if constexpr (PASS == 1) {
        #pragma unroll
        for (int mt = 0; mt < 4; ++mt)
            #pragma unroll
            for (int v = 0; v < 4; ++v) {
                int r = ft * 128 + wr * 64 + mt * 16 + quad * 4 + v;
                float gg = grow[(size_t)n * SN + r];
                a1c[mt][v] = 0.5f * gg * L2E;
                a0c[mt][v] = (10.f - 0.5f * gg) * L2E;
            }
    }

    float runRow[4][4];
    #pragma unroll
    for (int mt = 0; mt < 4; ++mt)
        #pragma unroll
        for (int v = 0; v < 4; ++v) runRow[mt][v] = (PASS == 1) ? 0.f : -3.0e38f;

    f32x4 acc[4][4];
    #pragma unroll
    for (int mt = 0; mt < 4; ++mt)
        #pragma unroll
        for (int nt = 0; nt < 4; ++nt) acc[mt][nt] = (f32x4){0.f, 0.f, 0.f, 0.f};

    float gl4[4] = {0.f, 0.f, 0.f, 0.f}, al4[4] = {0.f, 0.f, 0.f, 0.f};

    for (int t = 0; t < TPC; ++t) {
        const f16* Lt = Lnb + (size_t)(chunk * TPC + t) * 128 * CN;

        // ===== half 0: compute buf0 (K 0..127), prefetch this tile's h1 -> buf1 =====
        stage_half(Lt, 1, buf[1], tid);
        if constexpr (PASS == 2) {
            #pragma unroll
            for (int nt = 0; nt < 4; ++nt) {
                int i = (chunk * TPC + t) * 128 + wc * 64 + nt * 16 + lrow;
                gl4[nt] = grow[(size_t)n * SN + i];
                al4[nt] = alpha[(size_t)n * SN + i];
            }
        }
        #pragma unroll
        for (int kk = 0; kk < 4; ++kk) {
            f16x8 bf[4];
            #pragma unroll
            for (int nt = 0; nt < 4; ++nt) {
                int row = wc * 64 + nt * 16 + lrow;
                bf[nt] = *(const f16x8*)&buf[0][row * 128 + ((kk * 4 + quad) ^ (row & 7)) * 8];
            }
            #pragma unroll
            for (int mt = 0; mt < 4; ++mt)
                #pragma unroll
                for (int nt = 0; nt < 4; ++nt)
                    acc[mt][nt] = __builtin_amdgcn_mfma_f32_16x16x32_f16(
                        af[mt][kk], bf[nt], acc[mt][nt], 0, 0, 0);
        }
        __syncthreads();   // h1 DMA done; buf0 reads done

        // ===== half 1: compute buf1 (K 128..255), prefetch next tile's h0 -> buf0 =====
        if (t + 1 < TPC)
            stage_half(Lnb + (size_t)(chunk * TPC + t + 1) * 128 * CN, 0, buf[0], tid);
        #pragma unroll
        for (int kk = 0; kk < 4; ++kk) {
            f16x8 bf[4];
            #pragma unroll
            for (int nt = 0; nt < 4; ++nt) {
                int row = wc * 64 + nt * 16 + lrow;
                bf[nt] = *(const f16x8*)&buf[1][row * 128 + ((kk * 4 + quad) ^ (row & 7)) * 8];
            }
            #pragma unroll
            for (int mt = 0; mt < 4; ++mt)
                #pragma unroll
                for (int nt = 0; nt < 4; ++nt)
                    acc[mt][nt] = __builtin_amdgcn_mfma_f32_16x16x32_f16(
                        af[mt][4 + kk], bf[nt], acc[mt][nt], 0, 0, 0);
        }

        // ---- per-tile epilogue (acc complete) ----
        if constexpr (PASS == 0) {
            #pragma unroll
            for (int mt = 0; mt < 4; ++mt)
                #pragma unroll
                for (int v = 0; v < 4; ++v) {
                    float m = fmaxf(fmaxf(acc[mt][0][v], acc[mt][1][v]),
                                    fmaxf(acc[mt][2][v], acc[mt][3][v]));
                    runRow[mt][v] = fmaxf(runRow[mt][v], m);
                }
        } else if constexpr (PASS == 1) {
            #pragma unroll
            for (int mt = 0; mt < 4; ++mt)
                #pragma unroll
                for (int v = 0; v < 4; ++v) {
                    float s = runRow[mt][v];
                    #pragma unroll
                    for (int nt = 0; nt < 4; ++nt) {
                        float arg = fminf(14.4269504089f,
                                          fmaf(acc[mt][nt][v], a1c[mt][v], a0c[mt][v]));
                        s += exp2f(arg);
                    }
                    runRow[mt][v] = s;
                }
        } else {
            #pragma unroll
            for (int mt = 0; mt < 4; ++mt)
                #pragma unroll
                for (int v = 0; v < 4; ++v) {
                    #pragma unroll
                    for (int nt = 0; nt < 4; ++nt) {
                        float raw = fmaxf(0.f, fmaf(acc[mt][nt][v], -0.5f, 0.5f));
                        float lc = fmaf(-gl4[nt], raw, al4[nt]);
                        runRow[mt][v] = fmaxf(runRow[mt][v], lc);
                    }
                }
        }
        #pragma unroll
        for (int mt = 0; mt < 4; ++mt)
            #pragma unroll
            for (int nt = 0; nt < 4; ++nt) acc[mt][nt] = (f32x4){0.f, 0.f, 0.f, 0.f};

        __syncthreads();   // next h0 DMA done; buf1 reads done
    }

    // ---- cross-lane / cross-wave reduction (alias redbuf onto buf) ----
    float* red = (float*)&buf[0][0];
    #pragma unroll
    for (int mt = 0; mt < 4; ++mt)
        #pragma unroll
        for (int v = 0; v < 4; ++v) {
            float val = runRow[mt][v];
            #pragma unroll
            for (int d = 1; d < 16; d <<= 1) {
                float o = __shfl_xor(val, d, 64);
                val = (PASS == 1) ? (val + o) : fmaxf(val, o);
            }
            if (lrow == 0) red[wc * 128 + wr * 64 + mt * 16 + quad * 4 + v] = val;
        }
    __syncthreads();
    if (tid < 128) {
        float a = red[tid], b = red[128 + tid];
        outP[(size_t)(n * NCHUNK + chunk) * SN + ft * 128 + tid] =
            (PASS == 1) ? (a + b) : fmaxf(a, b);
    }
}

// ---------------- small reduce kernels ----------------

__global__ __launch_bounds__(256) void r_g(const float* __restrict__ rowmaxP,
                                           float* __restrict__ grow) {
    int idx = blockIdx.x * 256 + threadIdx.x;
    int n = idx / SN, i = idx - n * SN;
    float m = -3.0e38f;
    for (int ch = 0; ch < NCHUNK; ++ch)
        m = fmaxf(m, rowmaxP[(size_t)(n * NCHUNK + ch) * SN + i]);
    float mr = fmaxf(0.f, (1.f - m) * 0.5f);
    grow[idx] = 10.f / (mr + 1e-5f);
}

__global__ __launch_bounds__(256) void r_alpha(const float* __restrict__ rowsumP,
                                               float* __restrict__ alpha) {
    int idx = blockIdx.x * 256 + threadIdx.x;
    int n = idx / SN, i = idx - n * SN;
    float s = 0.f;
    for (int ch = 0; ch < NCHUNK; ++ch)
        s += rowsumP[(size_t)(n * NCHUNK + ch) * SN + i];
    alpha[idx] = 10.f - logf(s);
}

__global__ __launch_bounds__(256) void r_colfin(const float* __restrict__ colmaxP,
                                                float* __restrict__ bsum) {
    int idx = blockIdx.x * 256 + threadIdx.x;
    int n = idx / SN, j = idx - n * SN;
    float m = -3.0e38f;
    for (int ch = 0; ch < NCHUNK; ++ch)
        m = fmaxf(m, colmaxP[(size_t)(n * NCHUNK + ch) * SN + j]);
    float v = expf(m);
    #pragma unroll
    for (int d = 1; d < 64; d <<= 1) v += __shfl_xor(v, d, 64);
    __shared__ float sb[4];
    if ((threadIdx.x & 63) == 0) sb[threadIdx.x >> 6] = v;
    __syncthreads();
    if (threadIdx.x == 0) bsum[blockIdx.x] = sb[0] + sb[1] + sb[2] + sb[3];
}

__global__ __launch_bounds__(64) void r_loss(const float* __restrict__ bsum,
                                             float* __restrict__ out) {
    int t = threadIdx.x;
    float v = (t < 50) ? bsum[t] : 0.f;
    float v0 = (t < 25) ? v : 0.f;
    float v1 = (t >= 25 && t < 50) ? v : 0.f;
    #pragma unroll
    for (int d = 1; d < 64; d <<= 1) {
        v0 += __shfl_xor(v0, d, 64);
        v1 += __shfl_xor(v1, d, 64);
    }
    if (t == 0) {
        float cs0 = v0 * (1.0f / SN), cs1 = v1 * (1.0f / SN);
        out[0] = -0.5f * (logf(cs0) + logf(cs1));
    }
}

// ---------------- launch ----------------

extern "C" void kernel_launch(void* const* d_in, const int* in_sizes, int n_in,
                              void* d_out, int out_size, void* d_ws, size_t ws_size,
                              hipStream_t stream) {
    const float* I = (const float*)d_in[0];
    const float* T = (const float*)d_in[1];
    float* out = (float*)d_out;

    float* wsf = (float*)d_ws;
    float* meanT = wsf;                       // 256
    float* sI    = meanT + 256;               // 12800
    float* sT    = sI + 12800;                // 12800
    float* grow  = sT + 12800;                // 12800
    float* alpha = grow + 12800;              // 12800
    float* rowmaxP = alpha + 12800;           // 64000
    float* rowsumP = rowmaxP + 64000;         // 64000
    float* colmaxP = rowsumP + 64000;         // 64000
    float* bsum = colmaxP + 64000;            // 64
    f16* Ah = (f16*)(bsum + 64);              // 2*6400*256 fp16 (centered I, [n,s,c])
    f16* Bh = Ah + (size_t)NBATCH * SN * CN;  // centered T; total ws ~14.1 MB

    k_meanT<<<256, 256, 0, stream>>>(T, meanT);
    k_xpose<<<dim3(100, 8, 2), 256, 0, stream>>>(I, meanT, Ah);
    k_xpose<<<dim3(100, 8, 2), 256, 0, stream>>>(T, meanT, Bh);
    k_rs<<<3200, 256, 0, stream>>>(Ah, Bh, sI, sT);
    k_scale<<<1600, 256, 0, stream>>>(Ah, sI);
    k_scale<<<1600, 256, 0, stream>>>(Bh, sT);

    dim3 gg(NTILES, NCHUNK, NBATCH);
    k_gemm<0><<<gg, 256, 0, stream>>>(Ah, Bh, nullptr, nullptr, rowmaxP);
    r_g<<<50, 256, 0, stream>>>(rowmaxP, grow);
    k_gemm<1><<<gg, 256, 0, stream>>>(Ah, Bh, grow, nullptr, rowsumP);
    r_alpha<<<50, 256, 0, stream>>>(rowsumP, alpha);
    k_gemm<2><<<gg, 256, 0, stream>>>(Bh, Ah, grow, alpha, colmaxP);
    r_colfin<<<50, 256, 0, stream>>>(colmaxP, bsum);
    r_loss<<<1, 64, 0, stream>>>(bsum, out);
}

// Round 3
// 281.309 us; speedup vs baseline: 1.0681x; 1.0294x over previous
//
#include <hip/hip_runtime.h>

#define SN 6400      // H*W
#define CN 256       // channels (= GEMM K)
#define NBATCH 2
#define NTILES 50    // SN / 128
#define NCHUNK 5     // tile chunks per pass
#define TPC 10       // tiles per chunk

typedef _Float16 f16;
typedef f16 f16x8 __attribute__((ext_vector_type(8)));
typedef f16 f16x4 __attribute__((ext_vector_type(4)));
typedef float f32x4 __attribute__((ext_vector_type(4)));

__device__ __forceinline__ void gld16(const f16* g, f16* l) {
    __builtin_amdgcn_global_load_lds(
        (__attribute__((address_space(1))) void*)(g),
        (__attribute__((address_space(3))) void*)(l), 16, 0, 0);
}

// Stage a 128-row x 64-half (16 KB) K-chunk into LDS.
// LDS row = 64 halfs = 128 B = 8 x 16B chunks. Chunk stored at LDS position c
// holds global chunk c ^ (row&7)  (swizzle applied on the SOURCE address; the
// DMA lane->LDS mapping is fixed: wave-uniform base + lane*16B).
__device__ __forceinline__ void stage64(const f16* __restrict__ gbase,
                                        f16* lbase, int tid) {
    #pragma unroll
    for (int it = 0; it < 4; ++it) {
        int q = it * 256 + tid;
        int row = q >> 3, c = q & 7;
        int cg = c ^ (row & 7);
        gld16(gbase + (size_t)row * CN + cg * 8,
              lbase + (size_t)(q & ~63) * 8);
    }
}

// ---------------- prep kernels ----------------

__global__ __launch_bounds__(256) void k_meanT(const float* __restrict__ T,
                                               float* __restrict__ meanT) {
    int c = blockIdx.x, t = threadIdx.x;
    const float* p0 = T + (size_t)c * SN;
    const float* p1 = T + (size_t)(CN + c) * SN;
    float s = 0.f;
    for (int i = t; i < SN; i += 256) s += p0[i] + p1[i];
    #pragma unroll
    for (int d = 1; d < 64; d <<= 1) s += __shfl_xor(s, d, 64);
    __shared__ float sb[4];
    if ((t & 63) == 0) sb[t >> 6] = s;
    __syncthreads();
    if (t == 0) meanT[c] = (sb[0] + sb[1] + sb[2] + sb[3]) * (1.0f / 12800.0f);
}

// transpose [n,c,s] -> [n,s,c], center, cast to fp16 (normalized later)
__global__ __launch_bounds__(256) void k_xpose(const float* __restrict__ X,
                                               const float* __restrict__ meanT,
                                               f16* __restrict__ out) {
    int n = blockIdx.z, c0 = blockIdx.y * 32, s0 = blockIdx.x * 64;
    __shared__ float tile[32][65];
    int tx = threadIdx.x & 63, ty = threadIdx.x >> 6;
    const float* Xb = X + ((size_t)n * CN + c0) * SN + s0;
    #pragma unroll
    for (int cy = ty; cy < 32; cy += 4)
        tile[cy][tx] = Xb[(size_t)cy * SN + tx] - meanT[c0 + cy];
    __syncthreads();
    int cc = threadIdx.x & 31, sy = threadIdx.x >> 5;
    f16* ob = out + ((size_t)n * SN + s0) * CN + c0;
    #pragma unroll
    for (int sr = sy; sr < 64; sr += 8)
        ob[(size_t)sr * CN + cc] = (f16)tile[cc][sr];
}

// rsqrt of sum-of-squares per row of the centered fp16 arrays (one wave per row)
__global__ __launch_bounds__(256) void k_rs(const f16* __restrict__ Ah,
                                            const f16* __restrict__ Bh,
                                            float* __restrict__ sI,
                                            float* __restrict__ sT) {
    int w = threadIdx.x >> 6, lane = threadIdx.x & 63;
    int idx = blockIdx.x * 4 + w;
    f16x4 a = *(const f16x4*)(Ah + (size_t)idx * CN + lane * 4);
    f16x4 b = *(const f16x4*)(Bh + (size_t)idx * CN + lane * 4);
    float sa = 0.f, sb = 0.f;
    #pragma unroll
    for (int j = 0; j < 4; ++j) {
        float x = (float)a[j]; sa += x * x;
        float y = (float)b[j]; sb += y * y;
    }
    #pragma unroll
    for (int d = 1; d < 64; d <<= 1) {
        sa += __shfl_xor(sa, d, 64);
        sb += __shfl_xor(sb, d, 64);
    }
    if (lane == 0) { sI[idx] = rsqrtf(sa); sT[idx] = rsqrtf(sb); }
}

// in-place normalize fp16 rows by fp32 scale
__global__ __launch_bounds__(256) void k_scale(f16* __restrict__ X,
                                               const float* __restrict__ s) {
    int id8 = blockIdx.x * 256 + threadIdx.x;
    int row = id8 >> 5;
    float sc = s[row];
    f16x8 v = *(f16x8*)(X + (size_t)id8 * 8);
    #pragma unroll
    for (int j = 0; j < 8; ++j) v[j] = (f16)((float)v[j] * sc);
    *(f16x8*)(X + (size_t)id8 * 8) = v;
}

// ---------------- fused GEMM passes (m97-shape: A and B both LDS-staged) ----
// Fixed tile = MFMA A operand (rows of output); loop tiles = B operand (cols).
// PASS 0: per-row max of cos                          (fixed = I rows i)
// PASS 1: per-row sum of exp((10 - g_i*raw)/ln2)      (fixed = I rows i)
// PASS 2: per-row max over cols of (alpha_c - g_c*raw)(fixed = T rows j)
template <int PASS>
__global__ __launch_bounds__(256, 3) void k_gemm(const f16* __restrict__ A,
                                                 const f16* __restrict__ B,
                                                 const float* __restrict__ grow,
                                                 const float* __restrict__ alpha,
                                                 float* __restrict__ outP) {
    const int n = blockIdx.z, chunk = blockIdx.y, ft = blockIdx.x;
    const int tid = threadIdx.x, lane = tid & 63, wv = tid >> 6;
    const int wr = wv >> 1, wc = wv & 1, quad = lane >> 4, lrow = lane & 15;

    __shared__ f16 Ab[128 * 64];    // 16 KB
    __shared__ f16 Bb[128 * 64];    // 16 KB

    const f16* At = A + ((size_t)n * SN + (size_t)ft * 128) * CN;
    const f16* Lnb = B + (size_t)n * SN * CN;

    // per-lane LDS read offsets (halfs), conflict-free via XOR swizzle
    int offA[4][2], offB[4][2];
    #pragma unroll
    for (int mt = 0; mt < 4; ++mt) {
        int ra = wr * 64 + mt * 16 + lrow;
        int rb = wc * 64 + mt * 16 + lrow;
        #pragma unroll
        for (int kk = 0; kk < 2; ++kk) {
            offA[mt][kk] = ra * 64 + (((kk * 4 + quad) ^ (ra & 7)) * 8);
            offB[mt][kk] = rb * 64 + (((kk * 4 + quad) ^ (rb & 7)) * 8);
        }
    }

    // PASS1 per-row exp coefficients (rows fixed for whole block)
    const float L2E = 1.44269504089f;
    float a0c[4][4], a1c[4][4];
    if constexpr (PASS == 1) {
        #pragma unroll
        for (int mt = 0; mt < 4; ++mt)
            #pragma unroll
            for (int v = 0; v < 4; ++v) {
                int r = ft * 128 + wr * 64 + mt * 16 + quad * 4 + v;
                float gg = grow[(size_t)n * SN + r];
                a1c[mt][v] = 0.5f * gg * L2E;
                a0c[mt][v] = (10.f - 0.5f * gg) * L2E;
            }
    }

    float runRow[4][4];
    #pragma unroll
    for (int mt = 0; mt < 4; ++mt)
        #pragma unroll
        for (int v = 0; v < 4; ++v) runRow[mt][v] = (PASS == 1) ? 0.f : -3.0e38f;

    float gl4[4], al4[4];

    for (int t = 0; t < TPC; ++t) {
        const f16* Lt = Lnb + (size_t)(chunk * TPC + t) * 128 * CN;

        if constexpr (PASS == 2) {
            #pragma unroll
            for (int nt = 0; nt < 4; ++nt) {
                int i = (chunk * TPC + t) * 128 + wc * 64 + nt * 16 + lrow;
                gl4[nt] = grow[(size_t)n * SN + i];
                al4[nt] = alpha[(size_t)n * SN + i];
            }
        }

        f32x4 acc[4][4];
        #pragma unroll
        for (int mt = 0; mt < 4; ++mt)
            #pragma unroll
            for (int nt = 0; nt < 4; ++nt) acc[mt][nt] = (f32x4){0.f, 0.f, 0.f, 0.f};

        #pragma unroll 1
        for (int h = 0; h < 4; ++h) {
            __syncthreads();                      // prev-stage reads complete
            stage64(At + h * 64, Ab, tid);
            stage64(Lt + h * 64, Bb, tid);
            __syncthreads();                      // DMA landed (vmcnt drain)
            #pragma unroll
            for (int kk = 0; kk < 2; ++kk) {
                f16x8 af[4], bf[4];
                #pragma unroll
                for (int mt = 0; mt < 4; ++mt) af[mt] = *(const f16x8*)&Ab[offA[mt][kk]];
                #pragma unroll
                for (int nt = 0; nt < 4; ++nt) bf[nt] = *(const f16x8*)&Bb[offB[nt][kk]];
                #pragma unroll
                for (int mt = 0; mt < 4; ++mt)
                    #pragma unroll
                    for (int nt = 0; nt < 4; ++nt)
                        acc[mt][nt] = __builtin_amdgcn_mfma_f32_16x16x32_f16(
                            af[mt], bf[nt], acc[mt][nt], 0, 0, 0);
            }
        }

        // ---- per-tile epilogue (registers only) ----
        if constexpr (PASS == 0) {
            #pragma unroll
            for (int mt = 0; mt < 4; ++mt)
                #pragma unroll
                for (int v = 0; v < 4; ++v) {
                    float m = fmaxf(fmaxf(acc[mt][0][v], acc[mt][1][v]),
                                    fmaxf(acc[mt][2][v], acc[mt][3][v]));
                    runRow[mt][v] = fmaxf(runRow[mt][v], m);
                }
        } else if constexpr (PASS == 1) {
            #pragma unroll
            for (int mt = 0; mt < 4; ++mt)
                #pragma unroll
                for (int v = 0; v < 4; ++v) {
                    float s = runRow[mt][v];
                    #pragma unroll
                    for (int nt = 0; nt < 4; ++nt) {
                        float arg = fminf(14.4269504089f,
                                          fmaf(acc[mt][nt][v], a1c[mt][v], a0c[mt][v]));
                        s += exp2f(arg);
                    }
                    runRow[mt][v] = s;
                }
        } else {
            #pragma unroll
            for (int mt = 0; mt < 4; ++mt)
                #pragma unroll
                for (int v = 0; v < 4; ++v) {
                    #pragma unroll
                    for (int nt = 0; nt < 4; ++nt) {
                        float raw = fmaxf(0.f, fmaf(acc[mt][nt][v], -0.5f, 0.5f));
                        float lc = fmaf(-gl4[nt], raw, al4[nt]);
                        runRow[mt][v] = fmaxf(runRow[mt][v], lc);
                    }
                }
        }
    }

    // ---- cross-lane / cross-wave reduction (alias red onto Ab) ----
    __syncthreads();
    float* red = (float*)&Ab[0];
    #pragma unroll
    for (int mt = 0; mt < 4; ++mt)
        #pragma unroll
        for (int v = 0; v < 4; ++v) {
            float val = runRow[mt][v];
            #pragma unroll
            for (int d = 1; d < 16; d <<= 1) {
                float o = __shfl_xor(val, d, 64);
                val = (PASS == 1) ? (val + o) : fmaxf(val, o);
            }
            if (lrow == 0) red[wc * 128 + wr * 64 + mt * 16 + quad * 4 + v] = val;
        }
    __syncthreads();
    if (tid < 128) {
        float a = red[tid], b = red[128 + tid];
        outP[(size_t)(n * NCHUNK + chunk) * SN + ft * 128 + tid] =
            (PASS == 1) ? (a + b) : fmaxf(a, b);
    }
}

// ---------------- small reduce kernels ----------------

__global__ __launch_bounds__(256) void r_g(const float* __restrict__ rowmaxP,
                                           float* __restrict__ grow) {
    int idx = blockIdx.x * 256 + threadIdx.x;
    int n = idx / SN, i = idx - n * SN;
    float m = -3.0e38f;
    for (int ch = 0; ch < NCHUNK; ++ch)
        m = fmaxf(m, rowmaxP[(size_t)(n * NCHUNK + ch) * SN + i]);
    float mr = fmaxf(0.f, (1.f - m) * 0.5f);
    grow[idx] = 10.f / (mr + 1e-5f);
}

__global__ __launch_bounds__(256) void r_alpha(const float* __restrict__ rowsumP,
                                               float* __restrict__ alpha) {
    int idx = blockIdx.x * 256 + threadIdx.x;
    int n = idx / SN, i = idx - n * SN;
    float s = 0.f;
    for (int ch = 0; ch < NCHUNK; ++ch)
        s += rowsumP[(size_t)(n * NCHUNK + ch) * SN + i];
    alpha[idx] = 10.f - logf(s);
}

__global__ __launch_bounds__(256) void r_colfin(const float* __restrict__ colmaxP,
                                                float* __restrict__ bsum) {
    int idx = blockIdx.x * 256 + threadIdx.x;
    int n = idx / SN, j = idx - n * SN;
    float m = -3.0e38f;
    for (int ch = 0; ch < NCHUNK; ++ch)
        m = fmaxf(m, colmaxP[(size_t)(n * NCHUNK + ch) * SN + j]);
    float v = expf(m);
    #pragma unroll
    for (int d = 1; d < 64; d <<= 1) v += __shfl_xor(v, d, 64);
    __shared__ float sb[4];
    if ((threadIdx.x & 63) == 0) sb[threadIdx.x >> 6] = v;
    __syncthreads();
    if (threadIdx.x == 0) bsum[blockIdx.x] = sb[0] + sb[1] + sb[2] + sb[3];
}

__global__ __launch_bounds__(64) void r_loss(const float* __restrict__ bsum,
                                             float* __restrict__ out) {
    int t = threadIdx.x;
    float v = (t < 50) ? bsum[t] : 0.f;
    float v0 = (t < 25) ? v : 0.f;
    float v1 = (t >= 25 && t < 50) ? v : 0.f;
    #pragma unroll
    for (int d = 1; d < 64; d <<= 1) {
        v0 += __shfl_xor(v0, d, 64);
        v1 += __shfl_xor(v1, d, 64);
    }
    if (t == 0) {
        float cs0 = v0 * (1.0f / SN), cs1 = v1 * (1.0f / SN);
        out[0] = -0.5f * (logf(cs0) + logf(cs1));
    }
}

// ---------------- launch ----------------

extern "C" void kernel_launch(void* const* d_in, const int* in_sizes, int n_in,
                              void* d_out, int out_size, void* d_ws, size_t ws_size,
                              hipStream_t stream) {
    const float* I = (const float*)d_in[0];
    const float* T = (const float*)d_in[1];
    float* out = (float*)d_out;

    float* wsf = (float*)d_ws;
    float* meanT = wsf;                       // 256
    float* sI    = meanT + 256;               // 12800
    float* sT    = sI + 12800;                // 12800
    float* grow  = sT + 12800;                // 12800
    float* alpha = grow + 12800;              // 12800
    float* rowmaxP = alpha + 12800;           // 64000
    float* rowsumP = rowmaxP + 64000;         // 64000
    float* colmaxP = rowsumP + 64000;         // 64000
    float* bsum = colmaxP + 64000;            // 64
    f16* Ah = (f16*)(bsum + 64);              // 2*6400*256 fp16 (centered I, [n,s,c])
    f16* Bh = Ah + (size_t)NBATCH * SN * CN;  // centered T; total ws ~14.1 MB

    k_meanT<<<256, 256, 0, stream>>>(T, meanT);
    k_xpose<<<dim3(100, 8, 2), 256, 0, stream>>>(I, meanT, Ah);
    k_xpose<<<dim3(100, 8, 2), 256, 0, stream>>>(T, meanT, Bh);
    k_rs<<<3200, 256, 0, stream>>>(Ah, Bh, sI, sT);
    k_scale<<<1600, 256, 0, stream>>>(Ah, sI);
    k_scale<<<1600, 256, 0, stream>>>(Bh, sT);

    dim3 gg(NTILES, NCHUNK, NBATCH);
    k_gemm<0><<<gg, 256, 0, stream>>>(Ah, Bh, nullptr, nullptr, rowmaxP);
    r_g<<<50, 256, 0, stream>>>(rowmaxP, grow);
    k_gemm<1><<<gg, 256, 0, stream>>>(Ah, Bh, grow, nullptr, rowsumP);
    r_alpha<<<50, 256, 0, stream>>>(rowsumP, alpha);
    k_gemm<2><<<gg, 256, 0, stream>>>(Bh, Ah, grow, alpha, colmaxP);
    r_colfin<<<50, 256, 0, stream>>>(colmaxP, bsum);
    r_loss<<<1, 64, 0, stream>>>(bsum, out);
}